// Round 2
// baseline (1970.590 us; speedup 1.0000x reference)
//
#include <hip/hip_runtime.h>
#include <hip/hip_bf16.h>
#include <cmath>

// Problem: N=64, T=512, D=256, H=256 (all fp32)
//   c   = x @ Wx + b          (N,T,H)  -- parallel GEMM (phase 1, into d_out)
//   h_t = tanh(c_t + h_{t-1} @ Wh)     -- sequential scan (phase 2, in place)
//
// Scan design (R1): LDS-instruction-minimal. 256 threads/block, 1 block per
// batch row (64 blocks). Thread (j32=tid&31, g=tid>>5) owns 8 columns
// {j32+32c} and k-range [32g,32g+32). Wh slice = 256 VGPRs/thread
// (launch_bounds(256,1) -> 1 wave/SIMD, 512-VGPR budget). h in LDS (32 b128
// broadcast reads/step/block); k-reduction via ds_add_f32 into a
// double-buffered accumulator pre-initialized with c_t (no reduce-read phase).

#define KDIM  256
#define HDIM  256
#define TSTEPS 512
#define NBATCH 64

__device__ __forceinline__ float fast_tanh(float s) {
    float a = fabsf(s);
    float e = __expf(-2.0f * a);                         // v_exp_f32 path
    float r = (1.0f - e) * __builtin_amdgcn_rcpf(1.0f + e);
    return s < 0.0f ? -r : r;
}

// ---------------- Phase 1: c = x @ Wx + b ----------------
// 128x128 tile, 256 threads, 8x8 outputs/thread, K-chunks of 32.
// A staged transposed As[k][m]; B natural Bs[k][n]. ld=132 (pad 4).
__global__ __launch_bounds__(256, 2) void xw_gemm(
    const float* __restrict__ x,    // (32768, 256)
    const float* __restrict__ Wx,   // (256, 256)
    const float* __restrict__ bias, // (256)
    float* __restrict__ out)        // (32768, 256)
{
    __shared__ float As[32][132];   // [k][m]
    __shared__ float Bs[32][132];   // [k][n]

    const int tid = threadIdx.x;
    const int mt = tid >> 4;        // 0..15 -> rows 8*mt..8*mt+7
    const int nt = tid & 15;        // 0..15 -> cols 8*nt..8*nt+7
    const int m0 = blockIdx.x * 128;
    const int n0 = blockIdx.y * 128;

    float acc[8][8];
#pragma unroll
    for (int i = 0; i < 8; ++i)
#pragma unroll
        for (int j = 0; j < 8; ++j) acc[i][j] = 0.f;

    for (int kc = 0; kc < KDIM; kc += 32) {
        // Stage A: 128 m-rows x 32 k. float4 along k, store transposed.
        {
            const int k4 = tid & 7;           // k-chunk 4*k4
            const int mr = tid >> 3;          // 0..31
#pragma unroll
            for (int p = 0; p < 4; ++p) {
                int mrow = mr + 32 * p;
                float4 v = *(const float4*)&x[(size_t)(m0 + mrow) * KDIM + kc + 4 * k4];
                As[4 * k4 + 0][mrow] = v.x;
                As[4 * k4 + 1][mrow] = v.y;
                As[4 * k4 + 2][mrow] = v.z;
                As[4 * k4 + 3][mrow] = v.w;
            }
        }
        // Stage B: 32 k-rows x 128 n. float4 along n, natural layout.
        {
            const int nn = 4 * (tid & 31);
            const int kr = tid >> 5;          // 0..7
#pragma unroll
            for (int p = 0; p < 4; ++p) {
                int krow = kr + 8 * p;
                float4 v = *(const float4*)&Wx[(size_t)(kc + krow) * HDIM + n0 + nn];
                *(float4*)&Bs[krow][nn] = v;
            }
        }
        __syncthreads();

#pragma unroll 4
        for (int k = 0; k < 32; ++k) {
            float4 a0 = *(const float4*)&As[k][8 * mt];
            float4 a1 = *(const float4*)&As[k][8 * mt + 4];
            float4 b0 = *(const float4*)&Bs[k][8 * nt];
            float4 b1 = *(const float4*)&Bs[k][8 * nt + 4];
            float av[8] = {a0.x, a0.y, a0.z, a0.w, a1.x, a1.y, a1.z, a1.w};
            float bv[8] = {b0.x, b0.y, b0.z, b0.w, b1.x, b1.y, b1.z, b1.w};
#pragma unroll
            for (int i = 0; i < 8; ++i)
#pragma unroll
                for (int j = 0; j < 8; ++j) acc[i][j] += av[i] * bv[j];
        }
        __syncthreads();
    }

    float4 bj0 = *(const float4*)&bias[n0 + 8 * nt];
    float4 bj1 = *(const float4*)&bias[n0 + 8 * nt + 4];
    float bb[8] = {bj0.x, bj0.y, bj0.z, bj0.w, bj1.x, bj1.y, bj1.z, bj1.w};
#pragma unroll
    for (int i = 0; i < 8; ++i) {
        float4 v0, v1;
        v0.x = acc[i][0] + bb[0]; v0.y = acc[i][1] + bb[1];
        v0.z = acc[i][2] + bb[2]; v0.w = acc[i][3] + bb[3];
        v1.x = acc[i][4] + bb[4]; v1.y = acc[i][5] + bb[5];
        v1.z = acc[i][6] + bb[6]; v1.w = acc[i][7] + bb[7];
        float* o = &out[(size_t)(m0 + 8 * mt + i) * HDIM + n0 + 8 * nt];
        *(float4*)&o[0] = v0;
        *(float4*)&o[4] = v1;
    }
}

// ---------------- Phase 2: sequential scan ----------------
__global__ __launch_bounds__(256, 1) void rnn_scan(
    const float* __restrict__ h0,   // (64, 256)
    const float* __restrict__ Wh,   // (256, 256)
    float* __restrict__ out)        // (64, 512, 256): holds c, overwritten by h
{
    const int r   = blockIdx.x;
    const int tid = threadIdx.x;
    const int j32 = tid & 31;       // column base
    const int g   = tid >> 5;       // k-group, k in [32g, 32g+32)

    __shared__ float hbuf[256];
    __shared__ float accb[2][256];

    // Persistent Wh slice: W[i][c] = Wh[32g+i][j32+32c]  (256 VGPRs)
    float W[32][8];
    {
        const float* wp = Wh + (size_t)(32 * g) * HDIM + j32;
#pragma unroll
        for (int i = 0; i < 32; ++i)
#pragma unroll
            for (int c = 0; c < 8; ++c)
                W[i][c] = wp[(size_t)i * HDIM + 32 * c];
    }

    float* outr = out + (size_t)r * TSTEPS * HDIM;

    hbuf[tid] = h0[(size_t)r * HDIM + tid];
    accb[0][tid] = outr[tid];        // pre-init step-0 accumulator with c_0
    __syncthreads();

    const float4* hv = (const float4*)(hbuf + 32 * g);

#pragma unroll 1
    for (int t = 0; t < TSTEPS; ++t) {
        float* cur = accb[t & 1];
        float* nxt = accb[1 - (t & 1)];

        // Prefetch c_{t+1} (phase-1 value; latency hidden behind FMA phase).
        int tn = t + 1 < TSTEPS ? t + 1 : TSTEPS - 1;
        float cnext = outr[(size_t)tn * HDIM + tid];

        // FMA phase: acc[c] = sum_{k in group} h[k] * Wh[k][j32+32c]
        float acc[8];
#pragma unroll
        for (int c = 0; c < 8; ++c) acc[c] = 0.f;
#pragma unroll
        for (int q = 0; q < 8; ++q) {
            float4 hh = hv[q];
#pragma unroll
            for (int c = 0; c < 8; ++c) {
                acc[c] += hh.x * W[4 * q + 0][c];
                acc[c] += hh.y * W[4 * q + 1][c];
                acc[c] += hh.z * W[4 * q + 2][c];
                acc[c] += hh.w * W[4 * q + 3][c];
            }
        }
        // k-reduction: 8 LDS float atomics (ds_add_f32), accumulator already
        // holds c_t.
#pragma unroll
        for (int c = 0; c < 8; ++c)
            atomicAdd(&cur[j32 + 32 * c], acc[c]);
        __syncthreads();

        // Tail (all 4 waves active): h_j = tanh(cur[j]); store, update hbuf,
        // pre-init next accumulator with c_{t+1}.
        float hn = fast_tanh(cur[tid]);
        outr[(size_t)t * HDIM + tid] = hn;
        hbuf[tid] = hn;               // FMA reads of hbuf all done (barrier)
        nxt[tid] = cnext;
        __syncthreads();
    }
}

extern "C" void kernel_launch(void* const* d_in, const int* in_sizes, int n_in,
                              void* d_out, int out_size, void* d_ws, size_t ws_size,
                              hipStream_t stream) {
    const float* x  = (const float*)d_in[0];   // (64,512,256)
    const float* h0 = (const float*)d_in[1];   // (64,256)
    const float* Wx = (const float*)d_in[2];   // (256,256)
    const float* Wh = (const float*)d_in[3];   // (256,256)
    const float* b  = (const float*)d_in[4];   // (256)
    float* out = (float*)d_out;                // (64,512,256)

    dim3 g1(32768 / 128, HDIM / 128);          // (256, 2)
    xw_gemm<<<g1, 256, 0, stream>>>(x, Wx, b, out);

    rnn_scan<<<NBATCH, 256, 0, stream>>>(h0, Wh, out);
}